// Round 10
// baseline (2136.120 us; speedup 1.0000x reference)
//
#include <hip/hip_runtime.h>
#include <hip/hip_bf16.h>

// LSTM: B=64, T=512, I=256, H=1024, O=1.
// R14: decisive experiment. Kernel A = R13 verbatim (512 blk x 256 thr,
// 8 XCD-local batch groups, system-scope h/flag traffic). Kernel B = R10
// verbatim (PROVEN, 2099us: 256 blk x 512 thr, 4 bgs, 2x replication).
// Host: occupancy-gate A (needs 2 blocks/CU for 512 co-resident blocks);
// fall back to B if A can't co-reside or its cooperative launch errors.
// R12/R13 failed with BIT-IDENTICAL absmax 0.124 across different coherence
// regimes ~= max|reference| => likely all-zero output from a silently
// failed 512-block cooperative launch (return code was never checked).
// This round disambiguates: pass+WG256 => A sound; pass+WG512 => launch
// failure confirmed; fail 0.124 => structural bug in A's geometry.

typedef __bf16 bf16_t;
typedef bf16_t b16x8 __attribute__((ext_vector_type(8)));
typedef float  f32x4 __attribute__((ext_vector_type(4)));
typedef unsigned u32x4 __attribute__((ext_vector_type(4)));

#define TQ 512
#define IQ 256
#define HQ 1024

union U8 { b16x8 b; unsigned long long q[2]; unsigned short u[8]; };
union HU { f32x4 f; b16x8 b; };

__device__ __forceinline__ float bf2f(unsigned short s) {
    return __uint_as_float(((unsigned)s) << 16);
}
__device__ __forceinline__ unsigned short f2bf(float f) {
    unsigned u = __float_as_uint(f);
    u += 0x7fff + ((u >> 16) & 1);   // RNE
    return (unsigned short)(u >> 16);
}
__device__ __forceinline__ b16x8 cvt84(float4 a, float4 b) {
    U8 r;
    r.u[0] = f2bf(a.x); r.u[1] = f2bf(a.y); r.u[2] = f2bf(a.z); r.u[3] = f2bf(a.w);
    r.u[4] = f2bf(b.x); r.u[5] = f2bf(b.y); r.u[6] = f2bf(b.z); r.u[7] = f2bf(b.w);
    return r.b;
}
__device__ __forceinline__ float frcp(float x) { return __builtin_amdgcn_rcpf(x); }
__device__ __forceinline__ float sigm(float x) { return frcp(1.f + __expf(-x)); }
__device__ __forceinline__ float tanh_f(float v) {
    float x = fminf(fmaxf(v, -15.f), 15.f);
    float e = __expf(2.f * x);
    return (e - 1.f) * frcp(e + 1.f);
}

// ---- system-scope (sc0 sc1) helpers (R10-proven encoding) ----
__device__ __forceinline__ unsigned ld_flag_sys(const unsigned* p) {
    unsigned v;
    asm volatile("global_load_dword %0, %1, off sc0 sc1\n\ts_waitcnt vmcnt(0)"
                 : "=v"(v) : "v"(p) : "memory");
    return v;
}
__device__ __forceinline__ void st_flag_sys(unsigned* p, unsigned v) {
    asm volatile("global_store_dword %0, %1, off sc0 sc1" :: "v"(p), "v"(v) : "memory");
}
__device__ __forceinline__ void st_h16_sys(unsigned short* p, unsigned short v) {
    asm volatile("global_store_short %0, %1, off sc0 sc1" :: "v"(p), "v"(v) : "memory");
}
// 4 x 16B loads (k-chunks 64B apart) + waitcnt in one asm block: outputs
// defined only at block end -> dependent MFMAs can't hoist above the wait.
__device__ __forceinline__ void ld_h4(b16x8* ah, const unsigned short* p) {
    HU a, b, c, d;
    asm volatile(
        "global_load_dwordx4 %0, %4, off sc0 sc1\n\t"
        "global_load_dwordx4 %1, %4, off offset:64 sc0 sc1\n\t"
        "global_load_dwordx4 %2, %4, off offset:128 sc0 sc1\n\t"
        "global_load_dwordx4 %3, %4, off offset:192 sc0 sc1\n\t"
        "s_waitcnt vmcnt(0)"
        : "=&v"(a.f), "=&v"(b.f), "=&v"(c.f), "=&v"(d.f) : "v"(p) : "memory");
    ah[0] = a.b; ah[1] = b.b; ah[2] = c.b; ah[3] = d.b;
}
__device__ __forceinline__ void ld_h2_dev(b16x8* ah, const unsigned short* p) {
    HU a, b;
    asm volatile(
        "global_load_dwordx4 %0, %2, off sc0 sc1\n\t"
        "global_load_dwordx4 %1, %2, off offset:16 sc0 sc1\n\t"
        "s_waitcnt vmcnt(0)"
        : "=&v"(a.f), "=&v"(b.f) : "v"(p) : "memory");
    ah[0] = a.b; ah[1] = b.b;
}
__device__ __forceinline__ u32x4 ld_flag4_dev(const unsigned* p) {
    u32x4 v;
    asm volatile("global_load_dwordx4 %0, %1, off sc0 sc1\n\ts_waitcnt vmcnt(0)"
                 : "=v"(v) : "v"(p) : "memory");
    return v;
}

// ======================= KERNEL A (R13 geometry) ==========================
// hb: [copy2][bg8][p2][b8][u1024] bf16
#define A_HCOPY_SH 131072
#define A_HBG_SH   16384
#define A_HPBUF_SH 8192
#define A_BCOPY_W  8192
#define A_OFF_FH    524288
#define A_OFF_BAR   655360
#define A_OFF_FBAR  720896
#define MEMSET_BYTES 753664
#define RED2(ww,g,u,b) (((((ww)*4 + (g))*16 + (u))*12) + (b))

__launch_bounds__(256, 2)
__global__ void lstm_a(const float* __restrict__ x,
                       const float* __restrict__ Wih,
                       const float* __restrict__ Whh,
                       const float* __restrict__ bih,
                       const float* __restrict__ bhh,
                       const float* __restrict__ fcW,
                       const float* __restrict__ fcb,
                       float* __restrict__ out,
                       char* __restrict__ ws)
{
    __shared__ float red[4 * 4 * 16 * 12];   // 12 KB partials

    unsigned short* hb   = (unsigned short*)ws;
    unsigned short* fh   = (unsigned short*)(ws + A_OFF_FH);
    unsigned*       bar  = (unsigned*)(ws + A_OFF_BAR);
    unsigned*       fbar = (unsigned*)(ws + A_OFF_FBAR);

    const int tid  = threadIdx.x;
    const int w    = tid >> 6;        // wave 0..3
    const int lane = tid & 63;
    const int bid  = blockIdx.x;
    const int bg   = bid & 7;         // batch group (8 batches)
    const int ug   = bid >> 3;        // unit group (16 units), 0..63
    const int par  = ug & 1;          // replica this block reads

    const int l16  = lane & 15;
    const int quad = lane >> 4;

    // ---- one-time: weight fragments into registers (bf16) ----
    b16x8 wih[2][4];     // x: wave K-slice 64 = 2 chunks of 32
    b16x8 whh[8][4];     // h: wave K-slice 256 = 8 chunks of 32
    {
        const int koff = quad * 8;
        #pragma unroll
        for (int g = 0; g < 4; ++g) {
            int row = g * HQ + ug * 16 + l16;
            #pragma unroll
            for (int c = 0; c < 2; ++c) {
                const float* p = Wih + (size_t)row * IQ + w * 64 + c * 32 + koff;
                wih[c][g] = cvt84(*(const float4*)p, *(const float4*)(p + 4));
            }
            #pragma unroll
            for (int j = 0; j < 8; ++j) {
                const float* q = Whh + (size_t)row * HQ + w * 256 + j * 32 + koff;
                whh[j][g] = cvt84(*(const float4*)q, *(const float4*)(q + 4));
            }
        }
    }

    const int hi  = (lane >> 5) & 1;
    const int eb  = 2 * w + hi;          // batch row 0..7
    const int dup = (lane >> 4) & 1;     // partial half (ww 0-1 vs 2-3)
    float c_st = 0.f, h_last = 0.f;
    float bias_g[4];
    #pragma unroll
    for (int g = 0; g < 4; ++g) {
        int gr = g * HQ + ug * 16 + l16;
        bias_g[g] = bih[gr] + bhh[gr];
    }

    const unsigned short* hrd0 = hb + (size_t)par * A_HCOPY_SH + (size_t)bg * A_HBG_SH
                               + (size_t)(l16 & 7) * 1024 + w * 256 + quad * 8;
    unsigned short* hwr0 = hb + (size_t)bg * A_HBG_SH + (size_t)eb * 1024 + ug * 16 + l16;
    const unsigned* myfl = bar + (size_t)par * A_BCOPY_W
                         + ((size_t)(bg * 64 + w * 16 + (lane >> 2)) * 16 + (lane & 3));
    unsigned* wfl0 = bar + ((size_t)(bg * 64 + ug) * 16 + w);
    unsigned* wfl1 = wfl0 + A_BCOPY_W;

    const float* xbase = x + ((size_t)(bg * 8 + (l16 & 7)) * TQ) * IQ + w * 64 + quad * 8;
    float4 xa = *(const float4*)(xbase);
    float4 xb = *(const float4*)(xbase + 4);
    float4 xc = *(const float4*)(xbase + 32);
    float4 xd = *(const float4*)(xbase + 36);

    for (int t = 0; t < TQ; ++t) {
        const int p = t & 1;

        b16x8 ax0 = cvt84(xa, xb);
        b16x8 ax1 = cvt84(xc, xd);
        f32x4 acc[4];
        #pragma unroll
        for (int g = 0; g < 4; ++g) {
            f32x4 z = {0.f, 0.f, 0.f, 0.f};
            acc[g] = __builtin_amdgcn_mfma_f32_16x16x32_bf16(ax0, wih[0][g], z, 0, 0, 0);
            acc[g] = __builtin_amdgcn_mfma_f32_16x16x32_bf16(ax1, wih[1][g], acc[g], 0, 0, 0);
        }

        if (t) {   // t=0: h0=0, skip poll+h (hbuf never read before written)
            const unsigned need = (unsigned)t;
            unsigned v = ld_flag_sys(myfl);
            while (!__all(v >= need)) v = ld_flag_sys(myfl);

            const unsigned short* hp = hrd0 + (size_t)p * A_HPBUF_SH;
            b16x8 ah[4];
            ld_h4(ah, hp);                            // k-chunks 0..3
            #pragma unroll
            for (int j = 0; j < 4; ++j) {
                #pragma unroll
                for (int g = 0; g < 4; ++g)
                    acc[g] = __builtin_amdgcn_mfma_f32_16x16x32_bf16(ah[j], whh[j][g], acc[g], 0, 0, 0);
            }
            ld_h4(ah, hp + 128);                      // k-chunks 4..7
            #pragma unroll
            for (int j = 0; j < 4; ++j) {
                #pragma unroll
                for (int g = 0; g < 4; ++g)
                    acc[g] = __builtin_amdgcn_mfma_f32_16x16x32_bf16(ah[j], whh[4 + j][g], acc[g], 0, 0, 0);
            }
        }

        __syncthreads();   // barrier A
        if (quad < 2) {
            #pragma unroll
            for (int g = 0; g < 4; ++g)
                *(f32x4*)&red[RED2(w, g, l16, quad * 4)] = acc[g];
        }
        __syncthreads();   // barrier B

        float s[4];
        #pragma unroll
        for (int g = 0; g < 4; ++g) {
            float a0 = red[RED2(dup * 2 + 0, g, l16, eb)]
                     + red[RED2(dup * 2 + 1, g, l16, eb)];
            s[g] = a0 + __shfl_xor(a0, 16);
        }
        {
            float gi = s[0] + bias_g[0];
            float gf = s[1] + bias_g[1];
            float gg = s[2] + bias_g[2];
            float go_ = s[3] + bias_g[3];
            float i_s = sigm(gi);
            float f_s = sigm(gf);
            float g_t = tanh_f(gg);
            float o_s = sigm(go_);
            float c = f_s * c_st + i_s * g_t;
            c_st = c;
            float h = o_s * tanh_f(c);
            h_last = h;
            if (!dup) {
                unsigned short hv = f2bf(h);
                st_h16_sys(hwr0 + (size_t)(p ^ 1) * A_HPBUF_SH, hv);
                st_h16_sys(hwr0 + A_HCOPY_SH + (size_t)(p ^ 1) * A_HPBUF_SH, hv);
            }
        }
        asm volatile("s_waitcnt vmcnt(0)" ::: "memory");
        if (lane == 0) {
            st_flag_sys(wfl0, (unsigned)(t + 1));
            st_flag_sys(wfl1, (unsigned)(t + 1));
        }

        size_t nt = (t + 1 < TQ) ? (size_t)(t + 1) * IQ : (size_t)t * IQ;
        xa = *(const float4*)(xbase + nt);
        xb = *(const float4*)(xbase + nt + 4);
        xc = *(const float4*)(xbase + nt + 32);
        xd = *(const float4*)(xbase + nt + 36);
    }

    if (!dup)
        st_h16_sys(fh + ((size_t)(bg * 8 + eb)) * 1024 + ug * 16 + l16, f2bf(h_last));
    asm volatile("s_waitcnt vmcnt(0)" ::: "memory");
    if (lane == 0) st_flag_sys(fbar + ((size_t)(bg * 64 + ug) * 16 + w), 1u);

    if (ug == 0) {
        const unsigned* pf = fbar + ((size_t)(bg * 64 + lane) * 16);
        for (;;) {
            u32x4 v = ld_flag4_dev(pf);
            if (__all(v[0] == 1u && v[1] == 1u && v[2] == 1u && v[3] == 1u)) break;
        }
        float fb = fcb[0];
        #pragma unroll
        for (int r = 0; r < 2; ++r) {
            int b = w * 2 + r;
            b16x8 hv[2];
            ld_h2_dev(hv, fh + ((size_t)(bg * 8 + b)) * 1024 + lane * 16);
            float sacc = 0.f;
            #pragma unroll
            for (int k = 0; k < 2; ++k) {
                U8 u; u.b = hv[k];
                #pragma unroll
                for (int e = 0; e < 8; ++e)
                    sacc += tanh_f(bf2f(u.u[e])) * fcW[lane * 16 + k * 8 + e];
            }
            #pragma unroll
            for (int off = 32; off > 0; off >>= 1)
                sacc += __shfl_down(sacc, off);
            if (lane == 0) out[bg * 8 + b] = sacc + fb;
        }
    }
}

// ================== KERNEL B (R10 verbatim, PROVEN 2099us) =================
#define RED_B(w,g,u,b) (((((w)*4 + (g))*16 + (u))*20) + (b))
#define B_HCOPY 131072   // shorts per copy
#define B_HPBUF 65536    // shorts per p-buffer
#define B_BCOPY 4096     // u32 per copy

__launch_bounds__(512, 2)
__global__ void lstm_b(const float* __restrict__ x,
                       const float* __restrict__ Wih,
                       const float* __restrict__ Whh,
                       const float* __restrict__ bih,
                       const float* __restrict__ bhh,
                       const float* __restrict__ fcW,
                       const float* __restrict__ fcb,
                       float* __restrict__ out,
                       unsigned short* __restrict__ hbuf, // [2][2][4][16][1024] bf16
                       unsigned int* __restrict__ bar)    // [2][4][64][16] u32
{
    __shared__ float red[8 * 4 * 16 * 20];   // 40 KB, single-buffered

    const int tid  = threadIdx.x;
    const int w    = tid >> 6;        // wave 0..7
    const int lane = tid & 63;
    const int bid  = blockIdx.x;
    const int bg   = bid & 3;         // batch group (16 batches)
    const int ug   = bid >> 2;        // unit group (16 hidden units)
    const int par  = ug & 1;          // which replica this block READS

    const int l16  = lane & 15;
    const int quad = lane >> 4;

    b16x8 wih[4];
    b16x8 whh[4][4];
    {
        const int koff = quad * 8;
        #pragma unroll
        for (int g = 0; g < 4; ++g) {
            int row = g * HQ + ug * 16 + l16;
            const float* p = Wih + (size_t)row * IQ + w * 32 + koff;
            float4 a = *(const float4*)p;
            float4 b = *(const float4*)(p + 4);
            wih[g] = cvt84(a, b);
            #pragma unroll
            for (int j = 0; j < 4; ++j) {
                int k0 = (w * 4 + j) * 32 + koff;
                const float* q = Whh + (size_t)row * HQ + k0;
                float4 c = *(const float4*)q;
                float4 e = *(const float4*)(q + 4);
                whh[j][g] = cvt84(c, e);
            }
        }
    }

    const int hi  = (lane >> 5) & 1;
    const int eb  = 2 * w + hi;
    const int dup = (lane >> 4) & 1;
    float c_st = 0.f;
    float bias_g[4];
    #pragma unroll
    for (int g = 0; g < 4; ++g) {
        int gr = g * HQ + ug * 16 + l16;
        bias_g[g] = bih[gr] + bhh[gr];
    }

    const unsigned short* hrd0 = hbuf + (size_t)par * B_HCOPY
                               + ((size_t)bg * 16 + l16) * HQ + w * 128 + quad * 8;
    unsigned short* hwr0 = hbuf + (size_t)bg * 16 * HQ + (size_t)eb * HQ + ug * 16 + l16;

    const unsigned int* myfl = bar + (size_t)par * B_BCOPY
                             + ((size_t)(bg * 64 + w * 8 + (lane >> 3)) * 16 + (lane & 7));
    unsigned int* wfl0 = bar + ((size_t)(bg * 64 + ug) * 16 + w);
    unsigned int* wfl1 = wfl0 + B_BCOPY;

    const float* xbase = x + ((size_t)(bg * 16 + l16) * TQ) * IQ + w * 32 + quad * 8;
    float4 xa = *(const float4*)(xbase);
    float4 xb = *(const float4*)(xbase + 4);

    for (int t = 0; t < TQ; ++t) {
        const int p = t & 1;

        b16x8 ax = cvt84(xa, xb);
        f32x4 acc[4];
        #pragma unroll
        for (int g = 0; g < 4; ++g) {
            f32x4 z = {0.f, 0.f, 0.f, 0.f};
            acc[g] = __builtin_amdgcn_mfma_f32_16x16x32_bf16(ax, wih[g], z, 0, 0, 0);
        }

        const unsigned need = (unsigned)t;
        {
            unsigned v = __hip_atomic_load(myfl, __ATOMIC_RELAXED,
                                           __HIP_MEMORY_SCOPE_AGENT);
            while (!__all(v >= need))
                v = __hip_atomic_load(myfl, __ATOMIC_RELAXED,
                                      __HIP_MEMORY_SCOPE_AGENT);
        }

        b16x8 ah[4];
        ld_h4(ah, hrd0 + (size_t)p * B_HPBUF);
        #pragma unroll
        for (int j = 0; j < 4; ++j) {
            #pragma unroll
            for (int g = 0; g < 4; ++g)
                acc[g] = __builtin_amdgcn_mfma_f32_16x16x32_bf16(ah[j], whh[j][g], acc[g], 0, 0, 0);
        }

        __syncthreads();   // barrier A
        #pragma unroll
        for (int g = 0; g < 4; ++g)
            *(f32x4*)&red[RED_B(w, g, l16, quad * 4)] = acc[g];
        __syncthreads();   // barrier B

        float s[4];
        #pragma unroll
        for (int g = 0; g < 4; ++g) {
            float a0 = red[RED_B(dup * 4 + 0, g, l16, eb)]
                     + red[RED_B(dup * 4 + 1, g, l16, eb)];
            float a1 = red[RED_B(dup * 4 + 2, g, l16, eb)]
                     + red[RED_B(dup * 4 + 3, g, l16, eb)];
            float as = a0 + a1;
            as += __shfl_xor(as, 16);
            s[g] = as;
        }
        {
            float gi = s[0] + bias_g[0];
            float gf = s[1] + bias_g[1];
            float gg = s[2] + bias_g[2];
            float go_ = s[3] + bias_g[3];
            float i_s = sigm(gi);
            float f_s = sigm(gf);
            float g_t = tanh_f(gg);
            float o_s = sigm(go_);
            float c = f_s * c_st + i_s * g_t;
            c_st = c;
            float h = o_s * tanh_f(c);
            if (!dup) {
                unsigned short hv = f2bf(h);
                __hip_atomic_store(hwr0 + (size_t)(p ^ 1) * B_HPBUF, hv,
                                   __ATOMIC_RELAXED, __HIP_MEMORY_SCOPE_AGENT);
                __hip_atomic_store(hwr0 + B_HCOPY + (size_t)(p ^ 1) * B_HPBUF, hv,
                                   __ATOMIC_RELAXED, __HIP_MEMORY_SCOPE_AGENT);
            }
        }
        asm volatile("s_waitcnt vmcnt(0)" ::: "memory");
        if (lane == 0) {
            __hip_atomic_store(wfl0, (unsigned)(t + 1),
                               __ATOMIC_RELAXED, __HIP_MEMORY_SCOPE_AGENT);
            __hip_atomic_store(wfl1, (unsigned)(t + 1),
                               __ATOMIC_RELAXED, __HIP_MEMORY_SCOPE_AGENT);
        }

        size_t nt = (t + 1 < TQ) ? (size_t)(t + 1) * IQ : (size_t)t * IQ;
        xa = *(const float4*)(xbase + nt);
        xb = *(const float4*)(xbase + nt + 4);
    }

    if (bid < 4) {
        #pragma unroll
        for (int pb = 0; pb < 8; ++pb) {
            const unsigned int* pf = bar + ((size_t)(bg * 64 + pb * 8 + (lane >> 3)) * 16 + (lane & 7));
            unsigned v = __hip_atomic_load(pf, __ATOMIC_RELAXED,
                                           __HIP_MEMORY_SCOPE_AGENT);
            while (!__all(v >= (unsigned)TQ))
                v = __hip_atomic_load(pf, __ATOMIC_RELAXED,
                                      __HIP_MEMORY_SCOPE_AGENT);
        }
        const unsigned short* hl = hbuf + (size_t)bg * 16 * HQ;  // copy0, buffer 0
        float fb = fcb[0];
        #pragma unroll
        for (int r = 0; r < 2; ++r) {
            int b = w * 2 + r;
            float sacc = 0.f;
            #pragma unroll
            for (int j = 0; j < 16; ++j) {
                int u = j * 64 + lane;
                unsigned short hv = __hip_atomic_load(hl + (size_t)b * HQ + u,
                                                      __ATOMIC_RELAXED,
                                                      __HIP_MEMORY_SCOPE_AGENT);
                sacc += tanh_f(bf2f(hv)) * fcW[u];
            }
            #pragma unroll
            for (int off = 32; off > 0; off >>= 1)
                sacc += __shfl_down(sacc, off);
            if (lane == 0) out[bg * 16 + b] = sacc + fb;
        }
    }
}

extern "C" void kernel_launch(void* const* d_in, const int* in_sizes, int n_in,
                              void* d_out, int out_size, void* d_ws, size_t ws_size,
                              hipStream_t stream) {
    (void)in_sizes; (void)n_in; (void)out_size; (void)ws_size;
    const float* x   = (const float*)d_in[0];
    const float* Wih = (const float*)d_in[1];
    const float* Whh = (const float*)d_in[2];
    const float* bih = (const float*)d_in[3];
    const float* bhh = (const float*)d_in[4];
    const float* fcW = (const float*)d_in[5];
    const float* fcb = (const float*)d_in[6];
    float* out = (float*)d_out;

    hipMemsetAsync(d_ws, 0, MEMSET_BYTES, stream);

    // Resolve A-vs-B once (host-side, capture-neutral occupancy query).
    static int mode = -1;
    if (mode < 0) {
        int nb = 0;
        hipError_t e = hipOccupancyMaxActiveBlocksPerMultiprocessor(
            &nb, reinterpret_cast<const void*>(lstm_a), 256, 0);
        mode = (e == hipSuccess && nb >= 2) ? 1 : 0;
    }

    if (mode == 1) {
        char* ws = (char*)d_ws;
        void* args[] = { &x, &Wih, &Whh, &bih, &bhh, &fcW, &fcb, &out, &ws };
        hipError_t e = hipLaunchCooperativeKernel(
            reinterpret_cast<void*>(lstm_a), dim3(512), dim3(256), args, 0, stream);
        if (e == hipSuccess) return;
        mode = 0;   // cooperative launch rejected -> fall back permanently
    }

    unsigned short* hbuf = (unsigned short*)d_ws;                  // 2 x 262144 B
    unsigned int*   bar  = (unsigned int*)((char*)d_ws + 524288);  // 2 x 16384 B
    void* argsb[] = { &x, &Wih, &Whh, &bih, &bhh, &fcW, &fcb, &out, &hbuf, &bar };
    hipLaunchCooperativeKernel(reinterpret_cast<void*>(lstm_b),
                               dim3(256), dim3(512), argsb, 0, stream);
}

// Round 11
// 2097.497 us; speedup vs baseline: 1.0184x; 1.0184x over previous
//
#include <hip/hip_runtime.h>
#include <hip/hip_bf16.h>

// LSTM: B=64, T=512, I=256, H=1024, O=1.
// R15 = R14-A + sc0-only FAST MODE (the experiment R12 was meant to run;
// R12/R13's identical 0.124 failures are now attributed to silent
// cooperative-launch failure — R14 proved the geometry with system scope).
//  - Kernel A: 512 blk x 256 thr, 8 XCD-local batch groups (bg = bid&7),
//    runtime-verified via HW_REG_XCC_ID + grid-wide vote. Fast mode: all
//    h/flag ops sc0-only (L1-bypass, L2-coherent) -> handoff chain runs at
//    intra-XCD L2 latency (~200-400cy/RT) instead of MALL (~1500-2500cy/RT).
//    Mismatch -> fallback scopes sc0+sc1 (== R14-A, proven).
//  - Epoch-tagged flags: value = (epoch<<11)|step, epoch word OUTSIDE the
//    memset region, poll requires EXACT epoch match + step >= t. Kills
//    stale-dirty-L2-line hazards across graph replays (sc0 stores leave
//    dirty L2 lines that hipMemsetAsync does not invalidate).
//  - t=0 skips poll+h (h0=0): hbuf never read before written this launch.
//  - final h published system-scope to fh + fbar for the cross-XCD
//    projection (ug==0 blocks).
//  - Host: occupancy-gate A, error-checked cooperative launch, fall back
//    to kernel B (R10 verbatim, proven 2099us) on any launch failure.

typedef __bf16 bf16_t;
typedef bf16_t b16x8 __attribute__((ext_vector_type(8)));
typedef float  f32x4 __attribute__((ext_vector_type(4)));
typedef unsigned u32x4 __attribute__((ext_vector_type(4)));

#define TQ 512
#define IQ 256
#define HQ 1024

union U8 { b16x8 b; unsigned long long q[2]; unsigned short u[8]; };
union HU { f32x4 f; b16x8 b; };

__device__ __forceinline__ float bf2f(unsigned short s) {
    return __uint_as_float(((unsigned)s) << 16);
}
__device__ __forceinline__ unsigned short f2bf(float f) {
    unsigned u = __float_as_uint(f);
    u += 0x7fff + ((u >> 16) & 1);   // RNE
    return (unsigned short)(u >> 16);
}
__device__ __forceinline__ b16x8 cvt84(float4 a, float4 b) {
    U8 r;
    r.u[0] = f2bf(a.x); r.u[1] = f2bf(a.y); r.u[2] = f2bf(a.z); r.u[3] = f2bf(a.w);
    r.u[4] = f2bf(b.x); r.u[5] = f2bf(b.y); r.u[6] = f2bf(b.z); r.u[7] = f2bf(b.w);
    return r.b;
}
__device__ __forceinline__ float frcp(float x) { return __builtin_amdgcn_rcpf(x); }
__device__ __forceinline__ float sigm(float x) { return frcp(1.f + __expf(-x)); }
__device__ __forceinline__ float tanh_f(float v) {
    float x = fminf(fmaxf(v, -15.f), 15.f);
    float e = __expf(2.f * x);
    return (e - 1.f) * frcp(e + 1.f);
}

// ---- scoped helpers: fast = sc0-only (intra-XCD L2); else sc0+sc1 ----
__device__ __forceinline__ unsigned ld_flag_f(const unsigned* p, bool fast) {
    unsigned v;
    if (fast) asm volatile("global_load_dword %0, %1, off sc0\n\ts_waitcnt vmcnt(0)"
                           : "=v"(v) : "v"(p) : "memory");
    else      asm volatile("global_load_dword %0, %1, off sc0 sc1\n\ts_waitcnt vmcnt(0)"
                           : "=v"(v) : "v"(p) : "memory");
    return v;
}
__device__ __forceinline__ void st_flag_f(unsigned* p, unsigned v, bool fast) {
    if (fast) asm volatile("global_store_dword %0, %1, off sc0" :: "v"(p), "v"(v) : "memory");
    else      asm volatile("global_store_dword %0, %1, off sc0 sc1" :: "v"(p), "v"(v) : "memory");
}
__device__ __forceinline__ void st_h16_f(unsigned short* p, unsigned short v, bool fast) {
    if (fast) asm volatile("global_store_short %0, %1, off sc0" :: "v"(p), "v"(v) : "memory");
    else      asm volatile("global_store_short %0, %1, off sc0 sc1" :: "v"(p), "v"(v) : "memory");
}
__device__ __forceinline__ void ld_h4_f(b16x8* ah, const unsigned short* p, bool fast) {
    HU a, b, c, d;
    if (fast) asm volatile(
        "global_load_dwordx4 %0, %4, off sc0\n\t"
        "global_load_dwordx4 %1, %4, off offset:64 sc0\n\t"
        "global_load_dwordx4 %2, %4, off offset:128 sc0\n\t"
        "global_load_dwordx4 %3, %4, off offset:192 sc0\n\t"
        "s_waitcnt vmcnt(0)"
        : "=&v"(a.f), "=&v"(b.f), "=&v"(c.f), "=&v"(d.f) : "v"(p) : "memory");
    else asm volatile(
        "global_load_dwordx4 %0, %4, off sc0 sc1\n\t"
        "global_load_dwordx4 %1, %4, off offset:64 sc0 sc1\n\t"
        "global_load_dwordx4 %2, %4, off offset:128 sc0 sc1\n\t"
        "global_load_dwordx4 %3, %4, off offset:192 sc0 sc1\n\t"
        "s_waitcnt vmcnt(0)"
        : "=&v"(a.f), "=&v"(b.f), "=&v"(c.f), "=&v"(d.f) : "v"(p) : "memory");
    ah[0] = a.b; ah[1] = b.b; ah[2] = c.b; ah[3] = d.b;
}
// system-scope helpers (final h publication / projection / kernel B)
__device__ __forceinline__ void st_h16_sys(unsigned short* p, unsigned short v) {
    asm volatile("global_store_short %0, %1, off sc0 sc1" :: "v"(p), "v"(v) : "memory");
}
__device__ __forceinline__ void st_flag_sys(unsigned* p, unsigned v) {
    asm volatile("global_store_dword %0, %1, off sc0 sc1" :: "v"(p), "v"(v) : "memory");
}
__device__ __forceinline__ void ld_h4_sys(b16x8* ah, const unsigned short* p) {
    ld_h4_f(ah, p, false);
}
__device__ __forceinline__ void ld_h2_dev(b16x8* ah, const unsigned short* p) {
    HU a, b;
    asm volatile(
        "global_load_dwordx4 %0, %2, off sc0 sc1\n\t"
        "global_load_dwordx4 %1, %2, off offset:16 sc0 sc1\n\t"
        "s_waitcnt vmcnt(0)"
        : "=&v"(a.f), "=&v"(b.f) : "v"(p) : "memory");
    ah[0] = a.b; ah[1] = b.b;
}
__device__ __forceinline__ u32x4 ld_flag4_dev(const unsigned* p) {
    u32x4 v;
    asm volatile("global_load_dwordx4 %0, %1, off sc0 sc1\n\ts_waitcnt vmcnt(0)"
                 : "=v"(v) : "v"(p) : "memory");
    return v;
}

// ======================= KERNEL A (R14-A + fast mode) ======================
// hb: [copy2][bg8][p2][b8][u1024] bf16
#define A_HCOPY_SH 131072
#define A_HBG_SH   16384
#define A_HPBUF_SH 8192
#define A_BCOPY_W  8192
#define A_OFF_FH    524288
#define A_OFF_BAR   655360
#define A_OFF_FBAR  720896
#define A_OFF_CTRL  753664     // arrivals@0 mismatch@16 go@32 (u32 offsets /4)
#define MEMSET_BYTES 753920
#define A_OFF_EPOCH 753920     // OUTSIDE memset: persistent launch epoch
#define RED2(ww,g,u,b) (((((ww)*4 + (g))*16 + (u))*12) + (b))

__launch_bounds__(256, 2)
__global__ void lstm_a(const float* __restrict__ x,
                       const float* __restrict__ Wih,
                       const float* __restrict__ Whh,
                       const float* __restrict__ bih,
                       const float* __restrict__ bhh,
                       const float* __restrict__ fcW,
                       const float* __restrict__ fcb,
                       float* __restrict__ out,
                       char* __restrict__ ws)
{
    __shared__ float red[4 * 4 * 16 * 12];   // 12 KB partials
    __shared__ unsigned bc[1];

    unsigned short* hb    = (unsigned short*)ws;
    unsigned short* fh    = (unsigned short*)(ws + A_OFF_FH);
    unsigned*       bar   = (unsigned*)(ws + A_OFF_BAR);
    unsigned*       fbar  = (unsigned*)(ws + A_OFF_FBAR);
    unsigned*       ctl   = (unsigned*)(ws + A_OFF_CTRL);
    unsigned*       epoch = (unsigned*)(ws + A_OFF_EPOCH);

    const int tid  = threadIdx.x;
    const int w    = tid >> 6;        // wave 0..3
    const int lane = tid & 63;
    const int bid  = blockIdx.x;
    const int bg   = bid & 7;         // batch group (8 batches) == XCD in fast mode
    const int ug   = bid >> 3;        // unit group (16 units), 0..63
    const int par  = ug & 1;          // replica this block reads

    const int l16  = lane & 15;
    const int quad = lane >> 4;

    // ---- handshake part 1: publish arrival + XCD check (overlaps W-loads) --
    if (tid == 0) {
        unsigned xcd;
        asm volatile("s_getreg_b32 %0, hwreg(HW_REG_XCC_ID)" : "=s"(xcd));
        if ((int)(xcd & 7) != bg)
            __hip_atomic_fetch_or(ctl + 4, 1u, __ATOMIC_RELAXED, __HIP_MEMORY_SCOPE_AGENT);
        __threadfence();
        __hip_atomic_fetch_add(ctl + 0, 1u, __ATOMIC_RELAXED, __HIP_MEMORY_SCOPE_AGENT);
    }

    // ---- one-time: weight fragments into registers (bf16) ----
    b16x8 wih[2][4];     // x: wave K-slice 64 = 2 chunks of 32
    b16x8 whh[8][4];     // h: wave K-slice 256 = 8 chunks of 32
    {
        const int koff = quad * 8;
        #pragma unroll
        for (int g = 0; g < 4; ++g) {
            int row = g * HQ + ug * 16 + l16;
            #pragma unroll
            for (int c = 0; c < 2; ++c) {
                const float* p = Wih + (size_t)row * IQ + w * 64 + c * 32 + koff;
                wih[c][g] = cvt84(*(const float4*)p, *(const float4*)(p + 4));
            }
            #pragma unroll
            for (int j = 0; j < 8; ++j) {
                const float* q = Whh + (size_t)row * HQ + w * 256 + j * 32 + koff;
                whh[j][g] = cvt84(*(const float4*)q, *(const float4*)(q + 4));
            }
        }
    }

    // ---- handshake part 2: resolve mode + epoch ----
    if (tid == 0) {
        unsigned g;
        if (bid == 0) {
            unsigned e = (__hip_atomic_fetch_add(epoch, 1u, __ATOMIC_RELAXED,
                                                 __HIP_MEMORY_SCOPE_AGENT) + 1u) & 0xFFFFFu;
            while (__hip_atomic_load(ctl + 0, __ATOMIC_RELAXED,
                                     __HIP_MEMORY_SCOPE_AGENT) < 512u) {}
            __threadfence();
            unsigned m = __hip_atomic_load(ctl + 4, __ATOMIC_RELAXED,
                                           __HIP_MEMORY_SCOPE_AGENT);
            g = (e << 2) | (m ? 2u : 1u);
            __hip_atomic_store(ctl + 8, g, __ATOMIC_RELAXED, __HIP_MEMORY_SCOPE_AGENT);
        } else {
            do {
                g = __hip_atomic_load(ctl + 8, __ATOMIC_RELAXED,
                                      __HIP_MEMORY_SCOPE_AGENT);
            } while (!g);
        }
        bc[0] = g;
    }
    __syncthreads();
    const unsigned go   = bc[0];
    const bool     fast = (go & 3u) == 1u;
    const unsigned etag = go >> 2;            // 20-bit epoch

    const int hi  = (lane >> 5) & 1;
    const int eb  = 2 * w + hi;          // batch row 0..7
    const int dup = (lane >> 4) & 1;     // partial half (ww 0-1 vs 2-3)
    float c_st = 0.f, h_last = 0.f;
    float bias_g[4];
    #pragma unroll
    for (int g = 0; g < 4; ++g) {
        int gr = g * HQ + ug * 16 + l16;
        bias_g[g] = bih[gr] + bhh[gr];
    }

    const unsigned short* hrd0 = hb + (size_t)par * A_HCOPY_SH + (size_t)bg * A_HBG_SH
                               + (size_t)(l16 & 7) * 1024 + w * 256 + quad * 8;
    unsigned short* hwr0 = hb + (size_t)bg * A_HBG_SH + (size_t)eb * 1024 + ug * 16 + l16;
    const unsigned* myfl = bar + (size_t)par * A_BCOPY_W
                         + ((size_t)(bg * 64 + w * 16 + (lane >> 2)) * 16 + (lane & 3));
    unsigned* wfl0 = bar + ((size_t)(bg * 64 + ug) * 16 + w);
    unsigned* wfl1 = wfl0 + A_BCOPY_W;

    const float* xbase = x + ((size_t)(bg * 8 + (l16 & 7)) * TQ) * IQ + w * 64 + quad * 8;
    float4 xa = *(const float4*)(xbase);
    float4 xb = *(const float4*)(xbase + 4);
    float4 xc = *(const float4*)(xbase + 32);
    float4 xd = *(const float4*)(xbase + 36);

    for (int t = 0; t < TQ; ++t) {
        const int p = t & 1;

        b16x8 ax0 = cvt84(xa, xb);
        b16x8 ax1 = cvt84(xc, xd);
        f32x4 acc[4];
        #pragma unroll
        for (int g = 0; g < 4; ++g) {
            f32x4 z = {0.f, 0.f, 0.f, 0.f};
            acc[g] = __builtin_amdgcn_mfma_f32_16x16x32_bf16(ax0, wih[0][g], z, 0, 0, 0);
            acc[g] = __builtin_amdgcn_mfma_f32_16x16x32_bf16(ax1, wih[1][g], acc[g], 0, 0, 0);
        }

        if (t) {   // t=0: h0=0, skip poll+h (hbuf never read before written)
            // poll: EXACT epoch match + step >= t (stale epochs can't pass)
            unsigned v = ld_flag_f(myfl, fast);
            while (!__all(((v >> 11) == etag) & ((v & 0x7FFu) >= (unsigned)t)))
                v = ld_flag_f(myfl, fast);

            const unsigned short* hp = hrd0 + (size_t)p * A_HPBUF_SH;
            b16x8 ah[4];
            ld_h4_f(ah, hp, fast);                    // k-chunks 0..3
            #pragma unroll
            for (int j = 0; j < 4; ++j) {
                #pragma unroll
                for (int g = 0; g < 4; ++g)
                    acc[g] = __builtin_amdgcn_mfma_f32_16x16x32_bf16(ah[j], whh[j][g], acc[g], 0, 0, 0);
            }
            ld_h4_f(ah, hp + 128, fast);              // k-chunks 4..7
            #pragma unroll
            for (int j = 0; j < 4; ++j) {
                #pragma unroll
                for (int g = 0; g < 4; ++g)
                    acc[g] = __builtin_amdgcn_mfma_f32_16x16x32_bf16(ah[j], whh[4 + j][g], acc[g], 0, 0, 0);
            }
        }

        __syncthreads();   // barrier A
        if (quad < 2) {
            #pragma unroll
            for (int g = 0; g < 4; ++g)
                *(f32x4*)&red[RED2(w, g, l16, quad * 4)] = acc[g];
        }
        __syncthreads();   // barrier B

        float s[4];
        #pragma unroll
        for (int g = 0; g < 4; ++g) {
            float a0 = red[RED2(dup * 2 + 0, g, l16, eb)]
                     + red[RED2(dup * 2 + 1, g, l16, eb)];
            s[g] = a0 + __shfl_xor(a0, 16);
        }
        {
            float gi = s[0] + bias_g[0];
            float gf = s[1] + bias_g[1];
            float gg = s[2] + bias_g[2];
            float go_ = s[3] + bias_g[3];
            float i_s = sigm(gi);
            float f_s = sigm(gf);
            float g_t = tanh_f(gg);
            float o_s = sigm(go_);
            float c = f_s * c_st + i_s * g_t;
            c_st = c;
            float h = o_s * tanh_f(c);
            h_last = h;
            if (!dup) {
                unsigned short hv = f2bf(h);
                st_h16_f(hwr0 + (size_t)(p ^ 1) * A_HPBUF_SH, hv, fast);
                st_h16_f(hwr0 + A_HCOPY_SH + (size_t)(p ^ 1) * A_HPBUF_SH, hv, fast);
            }
        }
        // drain h stores to coherency point, then per-wave epoch-tagged flags
        asm volatile("s_waitcnt vmcnt(0)" ::: "memory");
        if (lane == 0) {
            unsigned fv = (etag << 11) | (unsigned)(t + 1);
            st_flag_f(wfl0, fv, fast);
            st_flag_f(wfl1, fv, fast);
        }

        size_t nt = (t + 1 < TQ) ? (size_t)(t + 1) * IQ : (size_t)t * IQ;
        xa = *(const float4*)(xbase + nt);
        xb = *(const float4*)(xbase + nt + 4);
        xc = *(const float4*)(xbase + nt + 32);
        xd = *(const float4*)(xbase + nt + 36);
    }

    // ---- publish final h (system scope, cross-XCD) ----
    if (!dup)
        st_h16_sys(fh + ((size_t)(bg * 8 + eb)) * 1024 + ug * 16 + l16, f2bf(h_last));
    asm volatile("s_waitcnt vmcnt(0)" ::: "memory");
    if (lane == 0) st_flag_sys(fbar + ((size_t)(bg * 64 + ug) * 16 + w), 1u);

    if (ug == 0) {
        const unsigned* pf = fbar + ((size_t)(bg * 64 + lane) * 16);
        for (;;) {
            u32x4 v = ld_flag4_dev(pf);
            if (__all(v[0] == 1u && v[1] == 1u && v[2] == 1u && v[3] == 1u)) break;
        }
        float fb = fcb[0];
        #pragma unroll
        for (int r = 0; r < 2; ++r) {
            int b = w * 2 + r;
            b16x8 hv[2];
            ld_h2_dev(hv, fh + ((size_t)(bg * 8 + b)) * 1024 + lane * 16);
            float sacc = 0.f;
            #pragma unroll
            for (int k = 0; k < 2; ++k) {
                U8 u; u.b = hv[k];
                #pragma unroll
                for (int e = 0; e < 8; ++e)
                    sacc += tanh_f(bf2f(u.u[e])) * fcW[lane * 16 + k * 8 + e];
            }
            #pragma unroll
            for (int off = 32; off > 0; off >>= 1)
                sacc += __shfl_down(sacc, off);
            if (lane == 0) out[bg * 8 + b] = sacc + fb;
        }
    }
}

// ================== KERNEL B (R10 verbatim, PROVEN fallback) ===============
#define RED_B(w,g,u,b) (((((w)*4 + (g))*16 + (u))*20) + (b))
#define B_HCOPY 131072   // shorts per copy
#define B_HPBUF 65536    // shorts per p-buffer
#define B_BCOPY 4096     // u32 per copy

__launch_bounds__(512, 2)
__global__ void lstm_b(const float* __restrict__ x,
                       const float* __restrict__ Wih,
                       const float* __restrict__ Whh,
                       const float* __restrict__ bih,
                       const float* __restrict__ bhh,
                       const float* __restrict__ fcW,
                       const float* __restrict__ fcb,
                       float* __restrict__ out,
                       unsigned short* __restrict__ hbuf,
                       unsigned int* __restrict__ bar)
{
    __shared__ float red[8 * 4 * 16 * 20];   // 40 KB

    const int tid  = threadIdx.x;
    const int w    = tid >> 6;
    const int lane = tid & 63;
    const int bid  = blockIdx.x;
    const int bg   = bid & 3;
    const int ug   = bid >> 2;
    const int par  = ug & 1;

    const int l16  = lane & 15;
    const int quad = lane >> 4;

    b16x8 wih[4];
    b16x8 whh[4][4];
    {
        const int koff = quad * 8;
        #pragma unroll
        for (int g = 0; g < 4; ++g) {
            int row = g * HQ + ug * 16 + l16;
            const float* p = Wih + (size_t)row * IQ + w * 32 + koff;
            float4 a = *(const float4*)p;
            float4 b = *(const float4*)(p + 4);
            wih[g] = cvt84(a, b);
            #pragma unroll
            for (int j = 0; j < 4; ++j) {
                int k0 = (w * 4 + j) * 32 + koff;
                const float* q = Whh + (size_t)row * HQ + k0;
                float4 c = *(const float4*)q;
                float4 e = *(const float4*)(q + 4);
                whh[j][g] = cvt84(c, e);
            }
        }
    }

    const int hi  = (lane >> 5) & 1;
    const int eb  = 2 * w + hi;
    const int dup = (lane >> 4) & 1;
    float c_st = 0.f;
    float bias_g[4];
    #pragma unroll
    for (int g = 0; g < 4; ++g) {
        int gr = g * HQ + ug * 16 + l16;
        bias_g[g] = bih[gr] + bhh[gr];
    }

    const unsigned short* hrd0 = hbuf + (size_t)par * B_HCOPY
                               + ((size_t)bg * 16 + l16) * HQ + w * 128 + quad * 8;
    unsigned short* hwr0 = hbuf + (size_t)bg * 16 * HQ + (size_t)eb * HQ + ug * 16 + l16;

    const unsigned int* myfl = bar + (size_t)par * B_BCOPY
                             + ((size_t)(bg * 64 + w * 8 + (lane >> 3)) * 16 + (lane & 7));
    unsigned int* wfl0 = bar + ((size_t)(bg * 64 + ug) * 16 + w);
    unsigned int* wfl1 = wfl0 + B_BCOPY;

    const float* xbase = x + ((size_t)(bg * 16 + l16) * TQ) * IQ + w * 32 + quad * 8;
    float4 xa = *(const float4*)(xbase);
    float4 xb = *(const float4*)(xbase + 4);

    for (int t = 0; t < TQ; ++t) {
        const int p = t & 1;

        b16x8 ax = cvt84(xa, xb);
        f32x4 acc[4];
        #pragma unroll
        for (int g = 0; g < 4; ++g) {
            f32x4 z = {0.f, 0.f, 0.f, 0.f};
            acc[g] = __builtin_amdgcn_mfma_f32_16x16x32_bf16(ax, wih[g], z, 0, 0, 0);
        }

        const unsigned need = (unsigned)t;
        {
            unsigned v = __hip_atomic_load(myfl, __ATOMIC_RELAXED,
                                           __HIP_MEMORY_SCOPE_AGENT);
            while (!__all(v >= need))
                v = __hip_atomic_load(myfl, __ATOMIC_RELAXED,
                                      __HIP_MEMORY_SCOPE_AGENT);
        }

        b16x8 ah[4];
        ld_h4_sys(ah, hrd0 + (size_t)p * B_HPBUF);
        #pragma unroll
        for (int j = 0; j < 4; ++j) {
            #pragma unroll
            for (int g = 0; g < 4; ++g)
                acc[g] = __builtin_amdgcn_mfma_f32_16x16x32_bf16(ah[j], whh[j][g], acc[g], 0, 0, 0);
        }

        __syncthreads();
        #pragma unroll
        for (int g = 0; g < 4; ++g)
            *(f32x4*)&red[RED_B(w, g, l16, quad * 4)] = acc[g];
        __syncthreads();

        float s[4];
        #pragma unroll
        for (int g = 0; g < 4; ++g) {
            float a0 = red[RED_B(dup * 4 + 0, g, l16, eb)]
                     + red[RED_B(dup * 4 + 1, g, l16, eb)];
            float a1 = red[RED_B(dup * 4 + 2, g, l16, eb)]
                     + red[RED_B(dup * 4 + 3, g, l16, eb)];
            float as = a0 + a1;
            as += __shfl_xor(as, 16);
            s[g] = as;
        }
        {
            float gi = s[0] + bias_g[0];
            float gf = s[1] + bias_g[1];
            float gg = s[2] + bias_g[2];
            float go_ = s[3] + bias_g[3];
            float i_s = sigm(gi);
            float f_s = sigm(gf);
            float g_t = tanh_f(gg);
            float o_s = sigm(go_);
            float c = f_s * c_st + i_s * g_t;
            c_st = c;
            float h = o_s * tanh_f(c);
            if (!dup) {
                unsigned short hv = f2bf(h);
                __hip_atomic_store(hwr0 + (size_t)(p ^ 1) * B_HPBUF, hv,
                                   __ATOMIC_RELAXED, __HIP_MEMORY_SCOPE_AGENT);
                __hip_atomic_store(hwr0 + B_HCOPY + (size_t)(p ^ 1) * B_HPBUF, hv,
                                   __ATOMIC_RELAXED, __HIP_MEMORY_SCOPE_AGENT);
            }
        }
        asm volatile("s_waitcnt vmcnt(0)" ::: "memory");
        if (lane == 0) {
            __hip_atomic_store(wfl0, (unsigned)(t + 1),
                               __ATOMIC_RELAXED, __HIP_MEMORY_SCOPE_AGENT);
            __hip_atomic_store(wfl1, (unsigned)(t + 1),
                               __ATOMIC_RELAXED, __HIP_MEMORY_SCOPE_AGENT);
        }

        size_t nt = (t + 1 < TQ) ? (size_t)(t + 1) * IQ : (size_t)t * IQ;
        xa = *(const float4*)(xbase + nt);
        xb = *(const float4*)(xbase + nt + 4);
    }

    if (bid < 4) {
        #pragma unroll
        for (int pb = 0; pb < 8; ++pb) {
            const unsigned int* pf = bar + ((size_t)(bg * 64 + pb * 8 + (lane >> 3)) * 16 + (lane & 7));
            unsigned v = __hip_atomic_load(pf, __ATOMIC_RELAXED,
                                           __HIP_MEMORY_SCOPE_AGENT);
            while (!__all(v >= (unsigned)TQ))
                v = __hip_atomic_load(pf, __ATOMIC_RELAXED,
                                      __HIP_MEMORY_SCOPE_AGENT);
        }
        const unsigned short* hl = hbuf + (size_t)bg * 16 * HQ;
        float fb = fcb[0];
        #pragma unroll
        for (int r = 0; r < 2; ++r) {
            int b = w * 2 + r;
            float sacc = 0.f;
            #pragma unroll
            for (int j = 0; j < 16; ++j) {
                int u = j * 64 + lane;
                unsigned short hv = __hip_atomic_load(hl + (size_t)b * HQ + u,
                                                      __ATOMIC_RELAXED,
                                                      __HIP_MEMORY_SCOPE_AGENT);
                sacc += tanh_f(bf2f(hv)) * fcW[u];
            }
            #pragma unroll
            for (int off = 32; off > 0; off >>= 1)
                sacc += __shfl_down(sacc, off);
            if (lane == 0) out[bg * 16 + b] = sacc + fb;
        }
    }
}

extern "C" void kernel_launch(void* const* d_in, const int* in_sizes, int n_in,
                              void* d_out, int out_size, void* d_ws, size_t ws_size,
                              hipStream_t stream) {
    (void)in_sizes; (void)n_in; (void)out_size; (void)ws_size;
    const float* x   = (const float*)d_in[0];
    const float* Wih = (const float*)d_in[1];
    const float* Whh = (const float*)d_in[2];
    const float* bih = (const float*)d_in[3];
    const float* bhh = (const float*)d_in[4];
    const float* fcW = (const float*)d_in[5];
    const float* fcb = (const float*)d_in[6];
    float* out = (float*)d_out;

    hipMemsetAsync(d_ws, 0, MEMSET_BYTES, stream);

    // Resolve A-vs-B once (host-side, capture-neutral occupancy query).
    static int mode = -1;
    if (mode < 0) {
        int nb = 0;
        hipError_t e = hipOccupancyMaxActiveBlocksPerMultiprocessor(
            &nb, reinterpret_cast<const void*>(lstm_a), 256, 0);
        mode = (e == hipSuccess && nb >= 2) ? 1 : 0;
    }

    if (mode == 1) {
        char* ws = (char*)d_ws;
        void* args[] = { &x, &Wih, &Whh, &bih, &bhh, &fcW, &fcb, &out, &ws };
        hipError_t e = hipLaunchCooperativeKernel(
            reinterpret_cast<void*>(lstm_a), dim3(512), dim3(256), args, 0, stream);
        if (e == hipSuccess) return;
        mode = 0;   // cooperative launch rejected -> fall back permanently
    }

    unsigned short* hbuf = (unsigned short*)d_ws;                  // 2 x 262144 B
    unsigned int*   bar  = (unsigned int*)((char*)d_ws + 524288);  // 2 x 16384 B
    void* argsb[] = { &x, &Wih, &Whh, &bih, &bhh, &fcW, &fcb, &out, &hbuf, &bar };
    hipLaunchCooperativeKernel(reinterpret_cast<void*>(lstm_b),
                               dim3(256), dim3(512), argsb, 0, stream);
}